// Round 9
// baseline (393.926 us; speedup 1.0000x reference)
//
#include <hip/hip_runtime.h>

// SpectralGNNEncoder on MI355X.
// out = (mu, logvar):
//   h1 = relu(Agg1(x@W1) + b1)   (sym-norm scatter-add w/ self loops)
//   g  = mean(Agg2(h1@W2)) + b2 = ((1/N) c^T h1) @ W2 + b2,  c[i]=dinv[i]^2+dinv[i]*S[i]
// Round 9: fully atomic-free CSR build (global atomics cost ~30B HBM write-through
// each — measured r6/r7/r8). binA dual-streams edge records by dst/src shard;
// binB LDS-counts (cnt|deg packed) per (shard, region-slice); scanC builds per-slice
// cursor bases; binC scatters edges via LDS cursors into XCD-local CSR windows.
// pass1 / k_dinv / fillB / rank / sbasePk all deleted.

typedef __bf16 bf16x8 __attribute__((ext_vector_type(8)));
typedef float f32x4 __attribute__((ext_vector_type(4)));
typedef float f32x2 __attribute__((ext_vector_type(2)));
typedef unsigned long long u64;

__device__ __forceinline__ float bf2f(unsigned short u){
  return __uint_as_float(((unsigned)u) << 16);
}
__device__ __forceinline__ unsigned short f2bf(float f){
  unsigned u = __float_as_uint(f);
  u += 0x7fffu + ((u >> 16) & 1u);   // RNE
  return (unsigned short)(u >> 16);
}
__device__ __forceinline__ __bf16 us2bf(unsigned short u){
  __bf16 b; __builtin_memcpy(&b, &u, 2); return b;
}
__device__ __forceinline__ float ldf(const void* p, int i, int isf32){
  return isf32 ? ((const float*)p)[i] : bf2f(((const unsigned short*)p)[i]);
}
// fma 8 fp8 feats (packed in uint2) into acc[8]
__device__ __forceinline__ void fma8f8(float* acc, float n, uint2 h){
  f32x2 p0 = __builtin_amdgcn_cvt_pk_f32_fp8((int)h.x, false);
  f32x2 p1 = __builtin_amdgcn_cvt_pk_f32_fp8((int)h.x, true);
  f32x2 p2 = __builtin_amdgcn_cvt_pk_f32_fp8((int)h.y, false);
  f32x2 p3 = __builtin_amdgcn_cvt_pk_f32_fp8((int)h.y, true);
  acc[0] = fmaf(n, p0[0], acc[0]);
  acc[1] = fmaf(n, p0[1], acc[1]);
  acc[2] = fmaf(n, p1[0], acc[2]);
  acc[3] = fmaf(n, p1[1], acc[3]);
  acc[4] = fmaf(n, p2[0], acc[4]);
  acc[5] = fmaf(n, p2[1], acc[5]);
  acc[6] = fmaf(n, p3[0], acc[6]);
  acc[7] = fmaf(n, p3[1], acc[7]);
}
// wave-level: (offset, length) of shard s's run inside region r from 8-entry hist
__device__ __forceinline__ void runOfShard(const int* __restrict__ hist, int r, int s,
                                           int lane, int& off, int& len){
  int hv = (lane < 8) ? hist[r * 8 + lane] : 0;
  off = 0; len = 0;
  #pragma unroll
  for (int i = 0; i < 8; ++i){
    int h = __shfl(hv, i);
    if (i < s) off += h;
    if (i == s) len = h;
  }
}

// ---------- init: dtype sniff (flag=1 iff f32) + zero v ----------
__global__ void k_init(const unsigned* __restrict__ xw, int* __restrict__ flag,
                       float* __restrict__ v){
  __shared__ int s[256];
  int t = threadIdx.x;
  if (t < 128) v[t] = 0.0f;
  int cnt = 0;
  for (int k = t; k < 4096; k += 256){
    unsigned lo = xw[k] & 0xFFFFu;
    int e = (int)((lo >> 7) & 0xFFu);
    if ((e >= 100 && e <= 141) || (lo & 0x7FFFu) == 0) cnt++;
  }
  s[t] = cnt;
  __syncthreads();
  for (int off = 128; off > 0; off >>= 1){
    if (t < off) s[t] += s[t + off];
    __syncthreads();
  }
  if (t == 0) *flag = (s[0] < 2458) ? 1 : 0;
}

// ---------- binA: dual-stream partition of edge records.
// streamD: ((u64)dst<<32 | src<<15 | wq15) by dst-shard; streamS symmetric by src-shard.
__global__ void __launch_bounds__(256) k_binA(const int* __restrict__ src,
    const int* __restrict__ dst, const void* __restrict__ w,
    u64* __restrict__ stagD, u64* __restrict__ stagS,
    int* __restrict__ histD, int* __restrict__ histS,
    int E, int DSv, const int* __restrict__ flagp){
  __shared__ int gcnt[256];
  __shared__ int gincl[256];
  __shared__ u64 bufD[1024];
  __shared__ u64 bufS[1024];
  int tid = threadIdx.x, lane = tid & 63, wv = tid >> 6;
  gcnt[tid] = 0;
  __syncthreads();
  int isf32 = *flagp;
  u64 ltmask = (1ull << lane) - 1ull;
  int sh1v[4], off1v[4], sh2v[4], off2v[4];
  u64 r1v[4], r2v[4];
  #pragma unroll
  for (int k = 0; k < 4; ++k){
    int e = blockIdx.x * 1024 + k * 256 + tid;
    int sh1 = -1, sh2 = -1; u64 r1 = 0, r2 = 0;
    if (e < E){
      int s_ = src[e], d_ = dst[e];
      float wf = ldf(w, e, isf32);
      int nq = (int)(wf * 32768.0f + 0.5f);
      if (nq > 32767) nq = 32767;
      r1 = ((u64)(unsigned)d_ << 32) | ((u64)(unsigned)s_ << 15) | (unsigned)nq;
      r2 = ((u64)(unsigned)s_ << 32) | ((u64)(unsigned)d_ << 15) | (unsigned)nq;
      sh1 = d_ / DSv;
      sh2 = s_ / DSv;
    }
    int o1 = 0, o2 = 0;
    #pragma unroll
    for (int s = 0; s < 8; ++s){
      u64 m1 = __ballot(sh1 == s);
      if (sh1 == s){ o1 = __popcll(m1 & ltmask); if (!o1) gcnt[s * 16 + k * 4 + wv] = __popcll(m1); }
      u64 m2 = __ballot(sh2 == s);
      if (sh2 == s){ o2 = __popcll(m2 & ltmask); if (!o2) gcnt[128 + s * 16 + k * 4 + wv] = __popcll(m2); }
    }
    sh1v[k] = sh1; off1v[k] = o1; r1v[k] = r1;
    sh2v[k] = sh2; off2v[k] = o2; r2v[k] = r2;
  }
  __syncthreads();
  gincl[tid] = gcnt[tid];
  __syncthreads();
  for (int ofs = 1; ofs < 256; ofs <<= 1){
    int t2 = (tid >= ofs) ? gincl[tid - ofs] : 0;
    __syncthreads();
    gincl[tid] += t2;
    __syncthreads();
  }
  int tot1 = gincl[127];
  #pragma unroll
  for (int k = 0; k < 4; ++k){
    if (sh1v[k] >= 0){
      int i1 = sh1v[k] * 16 + k * 4 + wv;
      bufD[gincl[i1] - gcnt[i1] + off1v[k]] = r1v[k];
      int i2 = 128 + sh2v[k] * 16 + k * 4 + wv;
      bufS[gincl[i2] - gcnt[i2] - tot1 + off2v[k]] = r2v[k];
    }
  }
  __syncthreads();
  for (int t = tid; t < tot1; t += 256)
    stagD[(size_t)blockIdx.x * 1024 + t] = bufD[t];
  int tot2 = gincl[255] - tot1;
  for (int t = tid; t < tot2; t += 256)
    stagS[(size_t)blockIdx.x * 1024 + t] = bufS[t];
  if (tid < 8){
    int a  = gincl[tid * 16 + 15];
    int pr = tid ? gincl[tid * 16 - 1] : 0;
    histD[blockIdx.x * 8 + tid] = a - pr;
    int a2  = gincl[128 + tid * 16 + 15];
    int pr2 = gincl[128 + tid * 16 - 1];           // tid=0 -> gincl[127]=tot1
    histS[blockIdx.x * 8 + tid] = a2 - pr2;
  }
}

// ---------- binB: block (s=B&7, j=B>>3): LDS-count shard s's records in region
// slice j. Packed partial: (cnt:12 | degfix:20, scale 2^-13). No global atomics. ----------
__global__ void __launch_bounds__(256) k_binB(const u64* __restrict__ stagD,
    const int* __restrict__ histD, unsigned* __restrict__ cntdegP, int NREG, int DSv){
  __shared__ unsigned cd[12512];
  int tid = threadIdx.x, lane = tid & 63, wv = tid >> 6;
  int s = (int)blockIdx.x & 7, j = (int)blockIdx.x >> 3;
  for (int i = tid; i < DSv; i += 256) cd[i] = 0u;
  __syncthreads();
  int per = (NREG + 15) / 16;
  int r0 = j * per, r1 = r0 + per;
  if (r1 > NREG) r1 = NREG;
  for (int r = r0 + wv; r < r1; r += 4){
    int off, len;
    runOfShard(histD, r, s, lane, off, len);
    const u64* rp = stagD + (size_t)r * 1024 + off;
    for (int i = lane; i < len; i += 64){
      u64 rec = rp[i];
      int dl = (int)(rec >> 32) - s * DSv;
      if ((unsigned)dl < (unsigned)DSv)
        atomicAdd(&cd[dl], (1u << 20) | (unsigned)((rec & 32767u) >> 2));
    }
  }
  __syncthreads();
  unsigned* op = cntdegP + (size_t)blockIdx.x * DSv;   // blockIdx = j*8+s
  for (int i = tid; i < DSv; i += 256) op[i] = cd[i];
}

// ---------- scanA: merge 16 partials -> cnt, dinv; block-scan cnt -> rowptr ----------
__global__ void k_scanA(const unsigned* __restrict__ cntdegP, float* __restrict__ dinv,
                        int* __restrict__ cnt, int* __restrict__ rowptr,
                        int* __restrict__ bsum, int N, int DSv){
  __shared__ int sm[256];
  int i = blockIdx.x * 256 + threadIdx.x;
  int val = 0;
  if (i < N){
    int s = i / DSv, local = i - s * DSv;
    unsigned c = 0, dg = 0;
    #pragma unroll
    for (int j = 0; j < 16; ++j){
      unsigned p = cntdegP[(size_t)(j * 8 + s) * DSv + local];
      c += p >> 20;
      dg += p & 0xFFFFFu;
    }
    dinv[i] = rsqrtf(1.0f + (float)dg * (1.0f / 8192.0f));  // +1 self loop
    cnt[i] = (int)c;
    val = (int)c;
  }
  sm[threadIdx.x] = val;
  __syncthreads();
  for (int off = 1; off < 256; off <<= 1){
    int tmp = (threadIdx.x >= off) ? sm[threadIdx.x - off] : 0;
    __syncthreads();
    sm[threadIdx.x] += tmp;
    __syncthreads();
  }
  if (i < N) rowptr[i] = sm[threadIdx.x] - val;
  if (threadIdx.x == 255) bsum[blockIdx.x] = sm[255];
}

__global__ void k_scanB(const int* __restrict__ bsum, int* __restrict__ boffs, int NB){
  __shared__ int s[512];
  int t = threadIdx.x;
  int val = (t < NB) ? bsum[t] : 0;
  s[t] = val;
  __syncthreads();
  for (int off = 1; off < 512; off <<= 1){
    int tmp = (t >= off) ? s[t - off] : 0;
    __syncthreads();
    s[t] += tmp;
    __syncthreads();
  }
  boffs[t] = s[t] - val;
}

// ---------- scanC: finalize rowptr; build per-slice cursor bases P[j][i] ----------
__global__ void k_scanC(int* __restrict__ rowptr, const int* __restrict__ boffs,
                        const unsigned* __restrict__ cntdegP, int* __restrict__ P,
                        int N, int DSv){
  int i = blockIdx.x * 256 + threadIdx.x;
  if (i >= N) return;
  int rp = rowptr[i] + boffs[blockIdx.x];
  rowptr[i] = rp;
  int s = i / DSv, local = i - s * DSv;
  int run = rp;
  #pragma unroll
  for (int j = 0; j < 16; ++j){
    P[(size_t)j * N + i] = run;
    run += (int)(cntdegP[(size_t)(j * 8 + s) * DSv + local] >> 20);
  }
}

// ---------- binC: block (s,j): LDS cursors from P[j]; scatter edges[pos] directly
// into the XCD-local CSR window of shard s. No rank, no global atomics. ----------
__global__ void __launch_bounds__(256) k_binC(const u64* __restrict__ stagD,
    const int* __restrict__ histD, const int* __restrict__ P,
    unsigned* __restrict__ edges, int NREG, int N, int DSv, int E){
  __shared__ unsigned cur[12512];
  int tid = threadIdx.x, lane = tid & 63, wv = tid >> 6;
  int s = (int)blockIdx.x & 7, j = (int)blockIdx.x >> 3;
  for (int i = tid; i < DSv; i += 256){
    int node = s * DSv + i;
    cur[i] = (node < N) ? (unsigned)P[(size_t)j * N + node] : 0u;
  }
  __syncthreads();
  int per = (NREG + 15) / 16;
  int r0 = j * per, r1 = r0 + per;
  if (r1 > NREG) r1 = NREG;
  for (int r = r0 + wv; r < r1; r += 4){
    int off, len;
    runOfShard(histD, r, s, lane, off, len);
    const u64* rp = stagD + (size_t)r * 1024 + off;
    for (int i = lane; i < len; i += 64){
      u64 rec = rp[i];
      int dl = (int)(rec >> 32) - s * DSv;
      if ((unsigned)dl < (unsigned)DSv){
        unsigned pos = atomicAdd(&cur[dl], 1u);    // LDS returning atomic (cheap)
        if (pos < (unsigned)E) edges[pos] = (unsigned)rec;   // low32 = (src<<15)|wq
      }
    }
  }
}

// ---------- cfacB: block (s,j): LDS-accumulate S[src] += wq*dinv[dst] from
// src-sharded stream; dinv random read is L2-warm (400KB replicated). ----------
__global__ void __launch_bounds__(256) k_cfacB(const u64* __restrict__ stagS,
    const int* __restrict__ histS, const float* __restrict__ dinv,
    float* __restrict__ cfacP, int NREG, int DSv){
  __shared__ float SL[12512];
  int tid = threadIdx.x, lane = tid & 63, wv = tid >> 6;
  int s = (int)blockIdx.x & 7, j = (int)blockIdx.x >> 3;
  for (int i = tid; i < DSv; i += 256) SL[i] = 0.0f;
  __syncthreads();
  int per = (NREG + 15) / 16;
  int r0 = j * per, r1 = r0 + per;
  if (r1 > NREG) r1 = NREG;
  for (int r = r0 + wv; r < r1; r += 4){
    int off, len;
    runOfShard(histS, r, s, lane, off, len);
    const u64* rp = stagS + (size_t)r * 1024 + off;
    for (int i = lane; i < len; i += 64){
      u64 rec = rp[i];
      int sl_ = (int)(rec >> 32) - s * DSv;
      int d   = (int)((rec >> 15) & 0x1FFFFu);
      float wq = (float)(rec & 32767u) * (1.0f / 32768.0f);
      if ((unsigned)sl_ < (unsigned)DSv)
        atomicAdd(&SL[sl_], wq * dinv[d]);
    }
  }
  __syncthreads();
  float* op = cfacP + (size_t)blockIdx.x * DSv;       // blockIdx = j*8+s
  for (int i = tid; i < DSv; i += 256) op[i] = SL[i];
}

// ---------- cfacm: sum 16 partials; pack (dinv, cfac) and (rowptr, cnt) ----------
__global__ void k_cfacm(const float* __restrict__ cfacP, const float* __restrict__ dinv,
                        const int* __restrict__ rowptr, const int* __restrict__ cnt,
                        float2* __restrict__ dc, int2* __restrict__ rc, int N, int DSv){
  int i = blockIdx.x * 256 + threadIdx.x;
  if (i >= N) return;
  int s = i / DSv, ii = i - s * DSv;
  float S = 0.0f;
  #pragma unroll
  for (int j = 0; j < 16; ++j)
    S += cfacP[(size_t)(j * 8 + s) * DSv + ii];
  float di = dinv[i];
  dc[i] = make_float2(di, di * di + di * S);       // (dinv, cfac)
  rc[i] = make_int2(rowptr[i], cnt[i]);
}

// ---------- W1T[n*128+k] = W1[k*128+n], canonical bf16 ----------
__global__ void k_transpose(const void* __restrict__ W1, unsigned short* __restrict__ W1T,
                            const int* __restrict__ flagp){
  int gid = blockIdx.x * 256 + threadIdx.x;
  int isf32 = *flagp;
  int k = gid & 127, n = gid >> 7;
  W1T[gid] = isf32 ? f2bf(((const float*)W1)[k * 128 + n])
                   : ((const unsigned short*)W1)[k * 128 + n];
}

// ---------- H' = 8*dinv_row*(x@W1) as fp8, 4 feature-planes of 32 ----------
__global__ void __launch_bounds__(256) k_gemm(const void* __restrict__ xv,
                                              const __bf16* __restrict__ wt,
                                              const float* __restrict__ dinv,
                                              unsigned char* __restrict__ H, int N,
                                              const int* __restrict__ flagp){
  int wave = (blockIdx.x * blockDim.x + threadIdx.x) >> 6;
  int lane = threadIdx.x & 63;
  int row16 = wave << 4;
  if (row16 >= N) return;
  int isf32 = *flagp;
  int m = lane & 15, q = lane >> 4;
  size_t planeStride = (size_t)N * 32;
  f32x4 dv;
  {
    const float4 d4 = *(const float4*)(dinv + row16 + q * 4);
    dv[0] = 8.0f * d4.x; dv[1] = 8.0f * d4.y; dv[2] = 8.0f * d4.z; dv[3] = 8.0f * d4.w;
  }
  bf16x8 a0, a1, a2, a3;
  if (isf32){
    const float* ap = (const float*)xv + (size_t)(row16 + m) * 128 + q * 8;
    #pragma unroll
    for (int j = 0; j < 8; ++j){
      a0[j] = us2bf(f2bf(ap[j +  0]));
      a1[j] = us2bf(f2bf(ap[j + 32]));
      a2[j] = us2bf(f2bf(ap[j + 64]));
      a3[j] = us2bf(f2bf(ap[j + 96]));
    }
  } else {
    const __bf16* ap = (const __bf16*)xv + (size_t)(row16 + m) * 128 + q * 8;
    a0 = *(const bf16x8*)(ap +  0);
    a1 = *(const bf16x8*)(ap + 32);
    a2 = *(const bf16x8*)(ap + 64);
    a3 = *(const bf16x8*)(ap + 96);
  }
  for (int nt = 0; nt < 8; ++nt){
    const __bf16* bp = wt + (size_t)(nt * 16 + m) * 128 + q * 8;
    bf16x8 b0 = *(const bf16x8*)(bp +  0);
    bf16x8 b1 = *(const bf16x8*)(bp + 32);
    bf16x8 b2 = *(const bf16x8*)(bp + 64);
    bf16x8 b3 = *(const bf16x8*)(bp + 96);
    f32x4 acc = {0.f, 0.f, 0.f, 0.f};
    acc = __builtin_amdgcn_mfma_f32_16x16x32_bf16(a0, b0, acc, 0, 0, 0);
    acc = __builtin_amdgcn_mfma_f32_16x16x32_bf16(a1, b1, acc, 0, 0, 0);
    acc = __builtin_amdgcn_mfma_f32_16x16x32_bf16(a2, b2, acc, 0, 0, 0);
    acc = __builtin_amdgcn_mfma_f32_16x16x32_bf16(a3, b3, acc, 0, 0, 0);
    unsigned char* op = H + (size_t)(nt >> 1) * planeStride
                          + (size_t)(row16 + q * 4) * 32 + (nt & 1) * 16 + m;
    float v0 = acc[0] * dv[0], v1 = acc[1] * dv[1];
    float v2 = acc[2] * dv[2], v3 = acc[3] * dv[3];
    op[0]  = (unsigned char)(__builtin_amdgcn_cvt_pk_fp8_f32(v0, v0, 0, false) & 0xFF);
    op[32] = (unsigned char)(__builtin_amdgcn_cvt_pk_fp8_f32(v1, v1, 0, false) & 0xFF);
    op[64] = (unsigned char)(__builtin_amdgcn_cvt_pk_fp8_f32(v2, v2, 0, false) & 0xFF);
    op[96] = (unsigned char)(__builtin_amdgcn_cvt_pk_fp8_f32(v3, v3, 0, false) & 0xFF);
  }
}

// ---------- k_agg: XCD-sliced slot-parallel gather; 2-deep pipeline ----------
__global__ void __launch_bounds__(256) k_agg(const unsigned char* __restrict__ H,
    const int2* __restrict__ rc, const float2* __restrict__ dc,
    const unsigned* __restrict__ edges, const void* __restrict__ b1,
    float* __restrict__ v, int N, int nblk, const int* __restrict__ flagp){
  __shared__ float vsh[32];
  int tid = threadIdx.x;
  if (tid < 32) vsh[tid] = 0.0f;
  __syncthreads();
  int isf32 = *flagp;
  int lane = tid & 63;
  int wv = tid >> 6;                  // wave in block 0..3
  int slot = lane >> 2;               // 0..15
  int q = lane & 3;                   // feature quarter within slice
  int sl = (blockIdx.x & 7) >> 1;     // slice/plane 0..3
  int jblk = (int)(blockIdx.x >> 3) * 2 + (blockIdx.x & 1);   // rank within slice
  int slotg = (jblk * 4 + wv) * 16 + slot;
  int totslots = (nblk >> 3) * 2 * 4 * 16;
  const unsigned char* Hp = H + (size_t)sl * ((size_t)N * 32);
  int fbase = sl * 32 + q * 8;
  float bx[8];
  #pragma unroll
  for (int j = 0; j < 8; ++j) bx[j] = ldf(b1, fbase + j, isf32);
  float ax[8] = {0,0,0,0,0,0,0,0};
  for (int d = slotg; d < N; d += totslots){
    int2  rcv = rc[d];                 // (rowptr, cnt)
    float2 dcv = dc[d];                // (dinv, cfac)
    float acc[8] = {0,0,0,0,0,0,0,0};
    uint2 hs = *(const uint2*)(Hp + (size_t)d * 32 + q * 8);
    fma8f8(acc, 1.0f, hs);             // self-loop: weight 1 in H' space
    int p = rcv.x, pe = rcv.x + rcv.y;
    if (p < pe){
      unsigned r = edges[p];
      uint2 h = *(const uint2*)(Hp + (size_t)(r >> 15) * 32 + q * 8);
      while (++p < pe){
        unsigned rn = edges[p];        // next edge word in flight
        uint2 hn = *(const uint2*)(Hp + (size_t)(rn >> 15) * 32 + q * 8);  // next gather
        fma8f8(acc, (float)(r & 32767u) * (1.0f / 32768.0f), h);
        r = rn; h = hn;
      }
      fma8f8(acc, (float)(r & 32767u) * (1.0f / 32768.0f), h);
    }
    float scale = dcv.x * 0.125f;      // dinv_d / 8
    #pragma unroll
    for (int j = 0; j < 8; ++j){
      float rj = fmaxf(fmaf(scale, acc[j], bx[j]), 0.0f);
      ax[j] = fmaf(dcv.y, rj, ax[j]);
    }
  }
  // cross-slot reduce (lane bits 2..5), once per wave
  #pragma unroll
  for (int j = 0; j < 8; ++j){
    ax[j] += __shfl_xor(ax[j], 4);
    ax[j] += __shfl_xor(ax[j], 8);
    ax[j] += __shfl_xor(ax[j], 16);
    ax[j] += __shfl_xor(ax[j], 32);
  }
  if (slot == 0){
    #pragma unroll
    for (int j = 0; j < 8; ++j) atomicAdd(&vsh[q * 8 + j], ax[j]);
  }
  __syncthreads();
  if (tid < 32) atomicAdd(&v[sl * 32 + tid], vsh[tid]);
}

// ---------- tiny head ----------
__global__ void __launch_bounds__(128) k_head(const float* __restrict__ v,
    const void* __restrict__ W2, const void* __restrict__ b2,
    const void* __restrict__ Wmu, const void* __restrict__ bmu,
    const void* __restrict__ Wlv, const void* __restrict__ blv,
    void* __restrict__ outv, float invN, const int* __restrict__ flagp){
  __shared__ float gsh[128];
  __shared__ float tsh[128];
  int t = threadIdx.x;
  int isf32 = *flagp;
  gsh[t] = v[t] * invN;
  __syncthreads();
  float acc = ldf(b2, t, isf32);
  for (int k = 0; k < 128; ++k) acc = fmaf(gsh[k], ldf(W2, k * 128 + t, isf32), acc);
  tsh[t] = acc;
  __syncthreads();
  int j = t & 63;
  const void* Wp = (t < 64) ? Wmu : Wlv;
  float o = ldf((t < 64) ? bmu : blv, j, isf32);
  for (int k = 0; k < 128; ++k) o = fmaf(tsh[k], ldf(Wp, k * 64 + j, isf32), o);
  if (isf32) ((float*)outv)[t] = o;
  else       ((unsigned short*)outv)[t] = f2bf(o);
}

extern "C" void kernel_launch(void* const* d_in, const int* in_sizes, int n_in,
                              void* d_out, int out_size, void* d_ws, size_t ws_size,
                              hipStream_t stream) {
  const void* x   = d_in[0];
  const int*  ei  = (const int*)d_in[1];
  const void* w   = d_in[2];
  const void* W1  = d_in[3];
  const void* b1  = d_in[4];
  const void* W2  = d_in[5];
  const void* b2  = d_in[6];
  const void* Wmu = d_in[7];
  const void* bmu = d_in[8];
  const void* Wlv = d_in[9];
  const void* blv = d_in[10];

  const int N = in_sizes[0] / 128;     // 100000
  const int E = in_sizes[2];           // 1600000
  const int* src = ei;
  const int* dst = ei + E;

  char* wsb = (char*)d_ws;
  size_t off = 0;
  auto alloc = [&](size_t bytes) -> void* {
    off = (off + 255) & ~(size_t)255;
    void* p = wsb + off;
    off += bytes;
    return p;
  };
  const int NREG = (E + 1023) / 1024;  // 1563 regions
  const int DSv  = (N + 7) / 8;        // 12500 nodes per shard (<=12512 LDS)
  int*   flag     = (int*)  alloc(16);
  float* dinv     = (float*)alloc((size_t)N * 4);
  int*   cnt      = (int*)  alloc((size_t)N * 4);
  int*   rowptr   = (int*)  alloc((size_t)(N + 1) * 4);
  float2* dc      = (float2*)alloc((size_t)N * 8);
  int2*   rc      = (int2*) alloc((size_t)N * 8);
  int*   bsum     = (int*)  alloc(512 * 4);
  int*   boffs    = (int*)  alloc(512 * 4);
  float* v        = (float*)alloc(128 * 4);
  int*   histD    = (int*)  alloc((size_t)NREG * 8 * 4);
  int*   histS    = (int*)  alloc((size_t)NREG * 8 * 4);
  unsigned short* W1T = (unsigned short*)alloc(128 * 128 * 2);
  // regionP: P (16*N*4, scanC->binC) overlaid by cfacP (128*DSv*4, cfacB->cfacm).
  size_t P_b = (size_t)16 * N * 4, cfacP_b = (size_t)128 * DSv * 4;
  char* regionP = (char*)alloc(P_b > cfacP_b ? P_b : cfacP_b);
  int*   P     = (int*)regionP;
  float* cfacP = (float*)regionP;
  // regionE: cntdegP (128*DSv*4, binB->scanC) overlaid by edges (E*4, binC->agg).
  size_t cdg_b = (size_t)128 * DSv * 4, edges_b = (size_t)E * 4;
  char* regionE = (char*)alloc(cdg_b > edges_b ? cdg_b : edges_b);
  unsigned* cntdegP = (unsigned*)regionE;
  unsigned* edges   = (unsigned*)regionE;
  // regionD: stagD (NREG*1024*8, binA->binC) overlaid by H (N*128, gemm->agg).
  size_t stagD_b = (size_t)NREG * 1024 * 8, H_b = (size_t)N * 128;
  char* regionD = (char*)alloc(stagD_b > H_b ? stagD_b : H_b);
  u64*           stagD = (u64*)regionD;
  unsigned char* H     = (unsigned char*)regionD;
  u64* stagS = (u64*)alloc((size_t)NREG * 1024 * 8);
  (void)ws_size; (void)n_in; (void)out_size;

  const int nb_n = (N + 255) / 256;    // 391

  k_init<<<1, 256, 0, stream>>>((const unsigned*)x, flag, v);
  k_binA<<<NREG, 256, 0, stream>>>(src, dst, w, stagD, stagS, histD, histS,
                                   E, DSv, flag);
  k_binB<<<128, 256, 0, stream>>>(stagD, histD, cntdegP, NREG, DSv);
  k_scanA<<<nb_n, 256, 0, stream>>>(cntdegP, dinv, cnt, rowptr, bsum, N, DSv);
  k_scanB<<<1, 512, 0, stream>>>(bsum, boffs, nb_n);
  k_scanC<<<nb_n, 256, 0, stream>>>(rowptr, boffs, cntdegP, P, N, DSv);
  k_binC<<<128, 256, 0, stream>>>(stagD, histD, P, edges, NREG, N, DSv, E);
  k_cfacB<<<128, 256, 0, stream>>>(stagS, histS, dinv, cfacP, NREG, DSv);
  k_cfacm<<<nb_n, 256, 0, stream>>>(cfacP, dinv, rowptr, cnt, dc, rc, N, DSv);
  k_transpose<<<64, 256, 0, stream>>>(W1, W1T, flag);
  const int nwaves = (N + 15) / 16;
  const int nb_g = (nwaves + 3) / 4;
  k_gemm<<<nb_g, 256, 0, stream>>>(x, (const __bf16*)W1T, dinv, H, N, flag);
  const int nb_agg = 2048;
  k_agg<<<nb_agg, 256, 0, stream>>>(H, rc, dc, edges, b1, v, N, nb_agg, flag);
  k_head<<<1, 128, 0, stream>>>(v, W2, b2, Wmu, bmu, Wlv, blv,
                                d_out, 1.0f / (float)N, flag);
}

// Round 11
// 376.267 us; speedup vs baseline: 1.0469x; 1.0469x over previous
//
#include <hip/hip_runtime.h>

// SpectralGNNEncoder on MI355X.
// out = (mu, logvar):
//   h1 = relu(Agg1(x@W1) + b1)   (sym-norm scatter-add w/ self loops)
//   g  = mean(Agg2(h1@W2)) + b2 = ((1/N) c^T h1) @ W2 + b2,  c[i]=dinv[i]^2+dinv[i]*S[i]
// Round 11 (= round 10 + compile fix: us2bf by-value instead of &vec[j] memcpy):
// k_agg true software pipeline (4-deep edge ring; H-gather address uses an edge
// word fetched 2 iterations earlier; next-node prefetch). Build: 24 slices
// (192-block kernels), transpose merged into init, plain-fp8 H, norm folded at binC.

typedef __bf16 bf16x8 __attribute__((ext_vector_type(8)));
typedef float f32x4 __attribute__((ext_vector_type(4)));
typedef float f32x2 __attribute__((ext_vector_type(2)));
typedef unsigned long long u64;

#define NSL 24   // region slices for binB/binC/cfacB

__device__ __forceinline__ float bf2f(unsigned short u){
  return __uint_as_float(((unsigned)u) << 16);
}
__device__ __forceinline__ unsigned short f2bf(float f){
  unsigned u = __float_as_uint(f);
  u += 0x7fffu + ((u >> 16) & 1u);   // RNE
  return (unsigned short)(u >> 16);
}
__device__ __forceinline__ __bf16 us2bf(unsigned short u){
  __bf16 b; __builtin_memcpy(&b, &u, 2); return b;
}
__device__ __forceinline__ float ldf(const void* p, int i, int isf32){
  return isf32 ? ((const float*)p)[i] : bf2f(((const unsigned short*)p)[i]);
}
// fma 8 fp8 feats (packed in uint2) into acc[8]
__device__ __forceinline__ void fma8f8(float* acc, float n, uint2 h){
  f32x2 p0 = __builtin_amdgcn_cvt_pk_f32_fp8((int)h.x, false);
  f32x2 p1 = __builtin_amdgcn_cvt_pk_f32_fp8((int)h.x, true);
  f32x2 p2 = __builtin_amdgcn_cvt_pk_f32_fp8((int)h.y, false);
  f32x2 p3 = __builtin_amdgcn_cvt_pk_f32_fp8((int)h.y, true);
  acc[0] = fmaf(n, p0[0], acc[0]);
  acc[1] = fmaf(n, p0[1], acc[1]);
  acc[2] = fmaf(n, p1[0], acc[2]);
  acc[3] = fmaf(n, p1[1], acc[3]);
  acc[4] = fmaf(n, p2[0], acc[4]);
  acc[5] = fmaf(n, p2[1], acc[5]);
  acc[6] = fmaf(n, p3[0], acc[6]);
  acc[7] = fmaf(n, p3[1], acc[7]);
}
// wave-level: (offset, length) of shard s's run inside region r from 8-entry hist
__device__ __forceinline__ void runOfShard(const int* __restrict__ hist, int r, int s,
                                           int lane, int& off, int& len){
  int hv = (lane < 8) ? hist[r * 8 + lane] : 0;
  off = 0; len = 0;
  #pragma unroll
  for (int i = 0; i < 8; ++i){
    int h = __shfl(hv, i);
    if (i < s) off += h;
    if (i == s) len = h;
  }
}

// ---------- init: per-block dtype sniff + W1 transpose; block 0 writes flag, v ----------
__global__ void k_init(const unsigned* __restrict__ xw, int* __restrict__ flag,
                       const void* __restrict__ W1, unsigned short* __restrict__ W1T,
                       float* __restrict__ v){
  __shared__ int s[256];
  int t = threadIdx.x;
  int cnt = 0;
  for (int k = t; k < 4096; k += 256){
    unsigned lo = xw[k] & 0xFFFFu;
    int e = (int)((lo >> 7) & 0xFFu);
    if ((e >= 100 && e <= 141) || (lo & 0x7FFFu) == 0) cnt++;
  }
  s[t] = cnt;
  __syncthreads();
  for (int off = 128; off > 0; off >>= 1){
    if (t < off) s[t] += s[t + off];
    __syncthreads();
  }
  int isf32 = (s[0] < 2458) ? 1 : 0;
  if (blockIdx.x == 0){
    if (t == 0) *flag = isf32;
    if (t < 128) v[t] = 0.0f;
  }
  int gid = blockIdx.x * 256 + t;      // gid = n*128 + k, 64 blocks cover 16384
  int k = gid & 127, n = gid >> 7;
  W1T[gid] = isf32 ? f2bf(((const float*)W1)[k * 128 + n])
                   : ((const unsigned short*)W1)[k * 128 + n];
}

// ---------- binA: dual-stream partition of edge records.
// streamD: ((u64)dst<<32 | src<<15 | w15) by dst-shard; streamS symmetric by src-shard.
__global__ void __launch_bounds__(256) k_binA(const int* __restrict__ src,
    const int* __restrict__ dst, const void* __restrict__ w,
    u64* __restrict__ stagD, u64* __restrict__ stagS,
    int* __restrict__ histD, int* __restrict__ histS,
    int E, int DSv, const int* __restrict__ flagp){
  __shared__ int gcnt[256];
  __shared__ int gincl[256];
  __shared__ u64 bufD[1024];
  __shared__ u64 bufS[1024];
  int tid = threadIdx.x, lane = tid & 63, wv = tid >> 6;
  gcnt[tid] = 0;
  __syncthreads();
  int isf32 = *flagp;
  u64 ltmask = (1ull << lane) - 1ull;
  int sh1v[4], off1v[4], sh2v[4], off2v[4];
  u64 r1v[4], r2v[4];
  #pragma unroll
  for (int k = 0; k < 4; ++k){
    int e = blockIdx.x * 1024 + k * 256 + tid;
    int sh1 = -1, sh2 = -1; u64 r1 = 0, r2 = 0;
    if (e < E){
      int s_ = src[e], d_ = dst[e];
      float wf = ldf(w, e, isf32);
      int nq = (int)(wf * 32768.0f + 0.5f);
      if (nq > 32767) nq = 32767;
      r1 = ((u64)(unsigned)d_ << 32) | ((u64)(unsigned)s_ << 15) | (unsigned)nq;
      r2 = ((u64)(unsigned)s_ << 32) | ((u64)(unsigned)d_ << 15) | (unsigned)nq;
      sh1 = d_ / DSv;
      sh2 = s_ / DSv;
    }
    int o1 = 0, o2 = 0;
    #pragma unroll
    for (int s = 0; s < 8; ++s){
      u64 m1 = __ballot(sh1 == s);
      if (sh1 == s){ o1 = __popcll(m1 & ltmask); if (!o1) gcnt[s * 16 + k * 4 + wv] = __popcll(m1); }
      u64 m2 = __ballot(sh2 == s);
      if (sh2 == s){ o2 = __popcll(m2 & ltmask); if (!o2) gcnt[128 + s * 16 + k * 4 + wv] = __popcll(m2); }
    }
    sh1v[k] = sh1; off1v[k] = o1; r1v[k] = r1;
    sh2v[k] = sh2; off2v[k] = o2; r2v[k] = r2;
  }
  __syncthreads();
  gincl[tid] = gcnt[tid];
  __syncthreads();
  for (int ofs = 1; ofs < 256; ofs <<= 1){
    int t2 = (tid >= ofs) ? gincl[tid - ofs] : 0;
    __syncthreads();
    gincl[tid] += t2;
    __syncthreads();
  }
  int tot1 = gincl[127];
  #pragma unroll
  for (int k = 0; k < 4; ++k){
    if (sh1v[k] >= 0){
      int i1 = sh1v[k] * 16 + k * 4 + wv;
      bufD[gincl[i1] - gcnt[i1] + off1v[k]] = r1v[k];
      int i2 = 128 + sh2v[k] * 16 + k * 4 + wv;
      bufS[gincl[i2] - gcnt[i2] - tot1 + off2v[k]] = r2v[k];
    }
  }
  __syncthreads();
  for (int t = tid; t < tot1; t += 256)
    stagD[(size_t)blockIdx.x * 1024 + t] = bufD[t];
  int tot2 = gincl[255] - tot1;
  for (int t = tid; t < tot2; t += 256)
    stagS[(size_t)blockIdx.x * 1024 + t] = bufS[t];
  if (tid < 8){
    int a  = gincl[tid * 16 + 15];
    int pr = tid ? gincl[tid * 16 - 1] : 0;
    histD[blockIdx.x * 8 + tid] = a - pr;
    int a2  = gincl[128 + tid * 16 + 15];
    int pr2 = gincl[128 + tid * 16 - 1];           // tid=0 -> gincl[127]=tot1
    histS[blockIdx.x * 8 + tid] = a2 - pr2;
  }
}

// ---------- binB: block (s=B&7, j=B>>3 of NSL): LDS-count (cnt:12|degfix:20) ----------
__global__ void __launch_bounds__(256) k_binB(const u64* __restrict__ stagD,
    const int* __restrict__ histD, unsigned* __restrict__ cntdegP,
    int NREG, int per, int DSv){
  __shared__ unsigned cd[12512];
  int tid = threadIdx.x, lane = tid & 63, wv = tid >> 6;
  int s = (int)blockIdx.x & 7, j = (int)blockIdx.x >> 3;
  for (int i = tid; i < DSv; i += 256) cd[i] = 0u;
  __syncthreads();
  int r0 = j * per, r1 = r0 + per;
  if (r1 > NREG) r1 = NREG;
  for (int r = r0 + wv; r < r1; r += 4){
    int off, len;
    runOfShard(histD, r, s, lane, off, len);
    const u64* rp = stagD + (size_t)r * 1024 + off;
    for (int i = lane; i < len; i += 64){
      u64 rec = rp[i];
      int dl = (int)(rec >> 32) - s * DSv;
      if ((unsigned)dl < (unsigned)DSv)
        atomicAdd(&cd[dl], (1u << 20) | (unsigned)((rec & 32767u) >> 2));
    }
  }
  __syncthreads();
  unsigned* op = cntdegP + (size_t)blockIdx.x * DSv;   // blockIdx = j*8+s
  for (int i = tid; i < DSv; i += 256) op[i] = cd[i];
}

// ---------- scanA: merge NSL partials -> cnt, dinv; block-scan cnt -> rowptr ----------
__global__ void k_scanA(const unsigned* __restrict__ cntdegP, float* __restrict__ dinv,
                        int* __restrict__ cnt, int* __restrict__ rowptr,
                        int* __restrict__ bsum, int N, int DSv){
  __shared__ int sm[256];
  int i = blockIdx.x * 256 + threadIdx.x;
  int val = 0;
  if (i < N){
    int s = i / DSv, local = i - s * DSv;
    unsigned c = 0, dg = 0;
    #pragma unroll
    for (int j = 0; j < NSL; ++j){
      unsigned p = cntdegP[(size_t)(j * 8 + s) * DSv + local];
      c += p >> 20;
      dg += p & 0xFFFFFu;
    }
    dinv[i] = rsqrtf(1.0f + (float)dg * (1.0f / 8192.0f));  // +1 self loop
    cnt[i] = (int)c;
    val = (int)c;
  }
  sm[threadIdx.x] = val;
  __syncthreads();
  for (int off = 1; off < 256; off <<= 1){
    int tmp = (threadIdx.x >= off) ? sm[threadIdx.x - off] : 0;
    __syncthreads();
    sm[threadIdx.x] += tmp;
    __syncthreads();
  }
  if (i < N) rowptr[i] = sm[threadIdx.x] - val;
  if (threadIdx.x == 255) bsum[blockIdx.x] = sm[255];
}

__global__ void k_scanB(const int* __restrict__ bsum, int* __restrict__ boffs, int NB){
  __shared__ int s[512];
  int t = threadIdx.x;
  int val = (t < NB) ? bsum[t] : 0;
  s[t] = val;
  __syncthreads();
  for (int off = 1; off < 512; off <<= 1){
    int tmp = (t >= off) ? s[t - off] : 0;
    __syncthreads();
    s[t] += tmp;
    __syncthreads();
  }
  boffs[t] = s[t] - val;
}

// ---------- scanC: finalize rowptr; build per-slice cursor bases P[j][i] ----------
__global__ void k_scanC(int* __restrict__ rowptr, const int* __restrict__ boffs,
                        const unsigned* __restrict__ cntdegP, int* __restrict__ P,
                        int N, int DSv){
  int i = blockIdx.x * 256 + threadIdx.x;
  if (i >= N) return;
  int rp = rowptr[i] + boffs[blockIdx.x];
  rowptr[i] = rp;
  int s = i / DSv, local = i - s * DSv;
  int run = rp;
  #pragma unroll
  for (int j = 0; j < NSL; ++j){
    P[(size_t)j * N + i] = run;
    run += (int)(cntdegP[(size_t)(j * 8 + s) * DSv + local] >> 20);
  }
}

// ---------- binC: block (s,j): LDS cursors from P[j]; fold norm=dinv_s*w*dinv_d;
// scatter edges[pos] into the XCD-local CSR window. ----------
__global__ void __launch_bounds__(256) k_binC(const u64* __restrict__ stagD,
    const int* __restrict__ histD, const int* __restrict__ P,
    const float* __restrict__ dinv, unsigned* __restrict__ edges,
    int NREG, int per, int N, int DSv, int E){
  __shared__ unsigned cur[12512];
  int tid = threadIdx.x, lane = tid & 63, wv = tid >> 6;
  int s = (int)blockIdx.x & 7, j = (int)blockIdx.x >> 3;
  for (int i = tid; i < DSv; i += 256){
    int node = s * DSv + i;
    cur[i] = (node < N) ? (unsigned)P[(size_t)j * N + node] : 0u;
  }
  __syncthreads();
  int r0 = j * per, r1 = r0 + per;
  if (r1 > NREG) r1 = NREG;
  for (int r = r0 + wv; r < r1; r += 4){
    int off, len;
    runOfShard(histD, r, s, lane, off, len);
    const u64* rp = stagD + (size_t)r * 1024 + off;
    for (int i = lane; i < len; i += 64){
      u64 rec = rp[i];
      int dl = (int)(rec >> 32) - s * DSv;
      if ((unsigned)dl < (unsigned)DSv){
        int srcI = (int)((rec >> 15) & 0x1FFFFu);
        float nrm = dinv[srcI] * ((float)(rec & 32767u) * (1.0f / 32768.0f))
                  * dinv[s * DSv + dl];
        int nq = (int)(nrm * 32768.0f + 0.5f);
        if (nq > 32767) nq = 32767;
        unsigned pos = atomicAdd(&cur[dl], 1u);    // LDS returning atomic (cheap)
        if (pos < (unsigned)E) edges[pos] = ((unsigned)srcI << 15) | (unsigned)nq;
      }
    }
  }
}

// ---------- cfacB: block (s,j): LDS-accumulate S[src] += w*dinv[dst] ----------
__global__ void __launch_bounds__(256) k_cfacB(const u64* __restrict__ stagS,
    const int* __restrict__ histS, const float* __restrict__ dinv,
    float* __restrict__ cfacP, int NREG, int per, int DSv){
  __shared__ float SL[12512];
  int tid = threadIdx.x, lane = tid & 63, wv = tid >> 6;
  int s = (int)blockIdx.x & 7, j = (int)blockIdx.x >> 3;
  for (int i = tid; i < DSv; i += 256) SL[i] = 0.0f;
  __syncthreads();
  int r0 = j * per, r1 = r0 + per;
  if (r1 > NREG) r1 = NREG;
  for (int r = r0 + wv; r < r1; r += 4){
    int off, len;
    runOfShard(histS, r, s, lane, off, len);
    const u64* rp = stagS + (size_t)r * 1024 + off;
    for (int i = lane; i < len; i += 64){
      u64 rec = rp[i];
      int sl_ = (int)(rec >> 32) - s * DSv;
      int d   = (int)((rec >> 15) & 0x1FFFFu);
      float wq = (float)(rec & 32767u) * (1.0f / 32768.0f);
      if ((unsigned)sl_ < (unsigned)DSv)
        atomicAdd(&SL[sl_], wq * dinv[d]);
    }
  }
  __syncthreads();
  float* op = cfacP + (size_t)blockIdx.x * DSv;       // blockIdx = j*8+s
  for (int i = tid; i < DSv; i += 256) op[i] = SL[i];
}

// ---------- cfacm: sum NSL partials; pack (dinv^2, cfac) and (rowptr, cnt) ----------
__global__ void k_cfacm(const float* __restrict__ cfacP, const float* __restrict__ dinv,
                        const int* __restrict__ rowptr, const int* __restrict__ cnt,
                        float2* __restrict__ dc, int2* __restrict__ rc, int N, int DSv){
  int i = blockIdx.x * 256 + threadIdx.x;
  if (i >= N) return;
  int s = i / DSv, ii = i - s * DSv;
  float S = 0.0f;
  #pragma unroll
  for (int j = 0; j < NSL; ++j)
    S += cfacP[(size_t)(j * 8 + s) * DSv + ii];
  float di = dinv[i];
  dc[i] = make_float2(di * di, di * di + di * S);   // (self-weight, cfac)
  rc[i] = make_int2(rowptr[i], cnt[i]);
}

// ---------- H = x@W1 as plain fp8, 4 feature-planes of 32 ----------
__global__ void __launch_bounds__(256) k_gemm(const void* __restrict__ xv,
                                              const __bf16* __restrict__ wt,
                                              unsigned char* __restrict__ H, int N,
                                              const int* __restrict__ flagp){
  int wave = (blockIdx.x * blockDim.x + threadIdx.x) >> 6;
  int lane = threadIdx.x & 63;
  int row16 = wave << 4;
  if (row16 >= N) return;
  int isf32 = *flagp;
  int m = lane & 15, q = lane >> 4;
  size_t planeStride = (size_t)N * 32;
  bf16x8 a0, a1, a2, a3;
  if (isf32){
    const float* ap = (const float*)xv + (size_t)(row16 + m) * 128 + q * 8;
    #pragma unroll
    for (int j = 0; j < 8; ++j){
      a0[j] = us2bf(f2bf(ap[j +  0]));
      a1[j] = us2bf(f2bf(ap[j + 32]));
      a2[j] = us2bf(f2bf(ap[j + 64]));
      a3[j] = us2bf(f2bf(ap[j + 96]));
    }
  } else {
    const __bf16* ap = (const __bf16*)xv + (size_t)(row16 + m) * 128 + q * 8;
    a0 = *(const bf16x8*)(ap +  0);
    a1 = *(const bf16x8*)(ap + 32);
    a2 = *(const bf16x8*)(ap + 64);
    a3 = *(const bf16x8*)(ap + 96);
  }
  for (int nt = 0; nt < 8; ++nt){
    const __bf16* bp = wt + (size_t)(nt * 16 + m) * 128 + q * 8;
    bf16x8 b0 = *(const bf16x8*)(bp +  0);
    bf16x8 b1 = *(const bf16x8*)(bp + 32);
    bf16x8 b2 = *(const bf16x8*)(bp + 64);
    bf16x8 b3 = *(const bf16x8*)(bp + 96);
    f32x4 acc = {0.f, 0.f, 0.f, 0.f};
    acc = __builtin_amdgcn_mfma_f32_16x16x32_bf16(a0, b0, acc, 0, 0, 0);
    acc = __builtin_amdgcn_mfma_f32_16x16x32_bf16(a1, b1, acc, 0, 0, 0);
    acc = __builtin_amdgcn_mfma_f32_16x16x32_bf16(a2, b2, acc, 0, 0, 0);
    acc = __builtin_amdgcn_mfma_f32_16x16x32_bf16(a3, b3, acc, 0, 0, 0);
    unsigned char* op = H + (size_t)(nt >> 1) * planeStride
                          + (size_t)(row16 + q * 4) * 32 + (nt & 1) * 16 + m;
    op[0]  = (unsigned char)(__builtin_amdgcn_cvt_pk_fp8_f32(acc[0], acc[0], 0, false) & 0xFF);
    op[32] = (unsigned char)(__builtin_amdgcn_cvt_pk_fp8_f32(acc[1], acc[1], 0, false) & 0xFF);
    op[64] = (unsigned char)(__builtin_amdgcn_cvt_pk_fp8_f32(acc[2], acc[2], 0, false) & 0xFF);
    op[96] = (unsigned char)(__builtin_amdgcn_cvt_pk_fp8_f32(acc[3], acc[3], 0, false) & 0xFF);
  }
}

// ---------- k_agg: XCD-sliced slot-parallel gather, deep pipeline:
// 4-deep edge ring; H address uses edge word fetched 2 iterations earlier;
// next-node rc/dc/self-H prefetched. ----------
__global__ void __launch_bounds__(256) k_agg(const unsigned char* __restrict__ H,
    const int2* __restrict__ rc, const float2* __restrict__ dc,
    const unsigned* __restrict__ edges, const void* __restrict__ b1,
    float* __restrict__ v, int N, int nblk, const int* __restrict__ flagp){
  __shared__ float vsh[32];
  int tid = threadIdx.x;
  if (tid < 32) vsh[tid] = 0.0f;
  __syncthreads();
  int isf32 = *flagp;
  int lane = tid & 63;
  int wv = tid >> 6;                  // wave in block 0..3
  int slot = lane >> 2;               // 0..15
  int q = lane & 3;                   // feature quarter within slice
  int sl = (blockIdx.x & 7) >> 1;     // slice/plane 0..3
  int jblk = (int)(blockIdx.x >> 3) * 2 + (blockIdx.x & 1);   // rank within slice
  int slotg = (jblk * 4 + wv) * 16 + slot;
  int totslots = (nblk >> 3) * 2 * 4 * 16;
  const unsigned char* Hp = H + (size_t)sl * ((size_t)N * 32);
  int fbase = sl * 32 + q * 8;
  float bx[8];
  #pragma unroll
  for (int j = 0; j < 8; ++j) bx[j] = ldf(b1, fbase + j, isf32);
  float ax[8] = {0,0,0,0,0,0,0,0};
  int d = slotg;
  int2 rcv = make_int2(0, 0); float2 dcv = make_float2(0.f, 0.f);
  uint2 hs = make_uint2(0u, 0u);
  if (d < N){
    rcv = rc[d]; dcv = dc[d];
    hs = *(const uint2*)(Hp + (size_t)d * 32 + q * 8);
  }
  while (d < N){
    int dn = d + totslots;
    int2 rcn = make_int2(0, 0); float2 dcn = make_float2(0.f, 0.f);
    uint2 hsn = make_uint2(0u, 0u);
    if (dn < N){                       // next-node prefetch (independent chains)
      rcn = rc[dn]; dcn = dc[dn];
      hsn = *(const uint2*)(Hp + (size_t)dn * 32 + q * 8);
    }
    float acc[8] = {0,0,0,0,0,0,0,0};
    fma8f8(acc, dcv.x, hs);            // self-loop: weight dinv^2
    int start = rcv.x, len = rcv.y;
    if (len > 0){
      int last = start + len - 1;
      // clamped prefetch index: dup loads of last word are L1-hits; their
      // (e,h) pairs are never consumed beyond k<len.
      unsigned e0 = edges[start];
      unsigned e1 = edges[(start + 1 < last) ? start + 1 : last];
      unsigned e2 = edges[(start + 2 < last) ? start + 2 : last];
      unsigned e3 = edges[(start + 3 < last) ? start + 3 : last];
      uint2 h0 = *(const uint2*)(Hp + (size_t)(e0 >> 15) * 32 + q * 8);
      uint2 h1 = *(const uint2*)(Hp + (size_t)(e1 >> 15) * 32 + q * 8);
      for (int k = 0; k < len; ++k){
        int a = start + k + 4;
        unsigned en = edges[a < last ? a : last];                    // 4 ahead
        uint2 hn = *(const uint2*)(Hp + (size_t)(e2 >> 15) * 32 + q * 8); // e2: 2-iter-old word
        fma8f8(acc, (float)(e0 & 32767u) * (1.0f / 32768.0f), h0);
        e0 = e1; e1 = e2; e2 = e3; e3 = en;
        h0 = h1; h1 = hn;
      }
    }
    #pragma unroll
    for (int j = 0; j < 8; ++j){
      float rj = fmaxf(acc[j] + bx[j], 0.0f);
      ax[j] = fmaf(dcv.y, rj, ax[j]);
    }
    d = dn; rcv = rcn; dcv = dcn; hs = hsn;
  }
  // cross-slot reduce (lane bits 2..5), once per wave
  #pragma unroll
  for (int j = 0; j < 8; ++j){
    ax[j] += __shfl_xor(ax[j], 4);
    ax[j] += __shfl_xor(ax[j], 8);
    ax[j] += __shfl_xor(ax[j], 16);
    ax[j] += __shfl_xor(ax[j], 32);
  }
  if (slot == 0){
    #pragma unroll
    for (int j = 0; j < 8; ++j) atomicAdd(&vsh[q * 8 + j], ax[j]);
  }
  __syncthreads();
  if (tid < 32) atomicAdd(&v[sl * 32 + tid], vsh[tid]);
}

// ---------- tiny head ----------
__global__ void __launch_bounds__(128) k_head(const float* __restrict__ v,
    const void* __restrict__ W2, const void* __restrict__ b2,
    const void* __restrict__ Wmu, const void* __restrict__ bmu,
    const void* __restrict__ Wlv, const void* __restrict__ blv,
    void* __restrict__ outv, float invN, const int* __restrict__ flagp){
  __shared__ float gsh[128];
  __shared__ float tsh[128];
  int t = threadIdx.x;
  int isf32 = *flagp;
  gsh[t] = v[t] * invN;
  __syncthreads();
  float acc = ldf(b2, t, isf32);
  for (int k = 0; k < 128; ++k) acc = fmaf(gsh[k], ldf(W2, k * 128 + t, isf32), acc);
  tsh[t] = acc;
  __syncthreads();
  int j = t & 63;
  const void* Wp = (t < 64) ? Wmu : Wlv;
  float o = ldf((t < 64) ? bmu : blv, j, isf32);
  for (int k = 0; k < 128; ++k) o = fmaf(tsh[k], ldf(Wp, k * 64 + j, isf32), o);
  if (isf32) ((float*)outv)[t] = o;
  else       ((unsigned short*)outv)[t] = f2bf(o);
}

extern "C" void kernel_launch(void* const* d_in, const int* in_sizes, int n_in,
                              void* d_out, int out_size, void* d_ws, size_t ws_size,
                              hipStream_t stream) {
  const void* x   = d_in[0];
  const int*  ei  = (const int*)d_in[1];
  const void* w   = d_in[2];
  const void* W1  = d_in[3];
  const void* b1  = d_in[4];
  const void* W2  = d_in[5];
  const void* b2  = d_in[6];
  const void* Wmu = d_in[7];
  const void* bmu = d_in[8];
  const void* Wlv = d_in[9];
  const void* blv = d_in[10];

  const int N = in_sizes[0] / 128;     // 100000
  const int E = in_sizes[2];           // 1600000
  const int* src = ei;
  const int* dst = ei + E;

  char* wsb = (char*)d_ws;
  size_t off = 0;
  auto alloc = [&](size_t bytes) -> void* {
    off = (off + 255) & ~(size_t)255;
    void* p = wsb + off;
    off += bytes;
    return p;
  };
  const int NREG = (E + 1023) / 1024;  // 1563 regions
  const int PER  = (NREG + NSL - 1) / NSL;
  const int DSv  = (N + 7) / 8;        // 12500 nodes per shard (<=12512 LDS)
  int*   flag     = (int*)  alloc(16);
  float* dinv     = (float*)alloc((size_t)N * 4);
  int*   cnt      = (int*)  alloc((size_t)N * 4);
  int*   rowptr   = (int*)  alloc((size_t)(N + 1) * 4);
  float2* dc      = (float2*)alloc((size_t)N * 8);
  int2*   rc      = (int2*) alloc((size_t)N * 8);
  int*   bsum     = (int*)  alloc(512 * 4);
  int*   boffs    = (int*)  alloc(512 * 4);
  float* v        = (float*)alloc(128 * 4);
  int*   histD    = (int*)  alloc((size_t)NREG * 8 * 4);
  int*   histS    = (int*)  alloc((size_t)NREG * 8 * 4);
  unsigned short* W1T = (unsigned short*)alloc(128 * 128 * 2);
  // regionP: P (NSL*N*4, scanC->binC) overlaid by cfacP (NSL*8*DSv*4, cfacB->cfacm).
  // Safe: binC (reads P) completes before cfacB launches (same stream).
  size_t P_b = (size_t)NSL * N * 4, cfacP_b = (size_t)NSL * 8 * DSv * 4;
  char* regionP = (char*)alloc(P_b > cfacP_b ? P_b : cfacP_b);
  int*   P     = (int*)regionP;
  float* cfacP = (float*)regionP;
  // regionE: cntdegP (NSL*8*DSv*4, binB->scanC) overlaid by edges (E*4, binC->agg).
  size_t cdg_b = (size_t)NSL * 8 * DSv * 4, edges_b = (size_t)E * 4;
  char* regionE = (char*)alloc(cdg_b > edges_b ? cdg_b : edges_b);
  unsigned* cntdegP = (unsigned*)regionE;
  unsigned* edges   = (unsigned*)regionE;
  // regionD: stagD (NREG*1024*8, binA->binC) overlaid by H (N*128, gemm->agg).
  size_t stagD_b = (size_t)NREG * 1024 * 8, H_b = (size_t)N * 128;
  char* regionD = (char*)alloc(stagD_b > H_b ? stagD_b : H_b);
  u64*           stagD = (u64*)regionD;
  unsigned char* H     = (unsigned char*)regionD;
  u64* stagS = (u64*)alloc((size_t)NREG * 1024 * 8);
  (void)ws_size; (void)n_in; (void)out_size;

  const int nb_n = (N + 255) / 256;    // 391

  k_init<<<64, 256, 0, stream>>>((const unsigned*)x, flag, W1, W1T, v);
  k_binA<<<NREG, 256, 0, stream>>>(src, dst, w, stagD, stagS, histD, histS,
                                   E, DSv, flag);
  k_binB<<<NSL * 8, 256, 0, stream>>>(stagD, histD, cntdegP, NREG, PER, DSv);
  k_scanA<<<nb_n, 256, 0, stream>>>(cntdegP, dinv, cnt, rowptr, bsum, N, DSv);
  k_scanB<<<1, 512, 0, stream>>>(bsum, boffs, nb_n);
  k_scanC<<<nb_n, 256, 0, stream>>>(rowptr, boffs, cntdegP, P, N, DSv);
  k_binC<<<NSL * 8, 256, 0, stream>>>(stagD, histD, P, dinv, edges,
                                      NREG, PER, N, DSv, E);
  k_cfacB<<<NSL * 8, 256, 0, stream>>>(stagS, histS, dinv, cfacP, NREG, PER, DSv);
  k_cfacm<<<nb_n, 256, 0, stream>>>(cfacP, dinv, rowptr, cnt, dc, rc, N, DSv);
  const int nwaves = (N + 15) / 16;
  const int nb_g = (nwaves + 3) / 4;
  k_gemm<<<nb_g, 256, 0, stream>>>(x, (const __bf16*)W1T, H, N, flag);
  const int nb_agg = 2048;
  k_agg<<<nb_agg, 256, 0, stream>>>(H, rc, dc, edges, b1, v, N, nb_agg, flag);
  k_head<<<1, 128, 0, stream>>>(v, W2, b2, Wmu, bmu, Wlv, blv,
                                d_out, 1.0f / (float)N, flag);
}